// Round 5
// baseline (184.407 us; speedup 1.0000x reference)
//
#include <hip/hip_runtime.h>

// DEC Student-t soft assignment, ALPHA=1 -> q_ij = 1/(1+d2_ij), row-normalized.
// d2 = ||h||^2 + ||c||^2 - 2 h.c ; cross term via bf16 MFMA, h_sq/c_sq exact fp32.
//
// R4 -> R5: fix the R4 race. ds_reads of a tile may only execute after
// {vmcnt drain ; s_barrier} — R4 read before the barrier, racing other waves'
// in-flight global_load_lds (absmax 4.6e-5). R5 keeps the m201 two-phase
// rhythm but puts the per-tile counted vmcnt at the END of ph2, right before
// ph2's barrier, so the next tile's ph1 reads are ordered after it:
//   ph1: {8 ds_read | stageA(T+3)} bar lgkm0 prio[16 MFMA] bar
//   ph2: {4 ds_read | stageB(T+3)} vmcnt(8) bar lgkm0 prio[16 MFMA] bar
// vmcnt ladder 8,8,...,8,4,0,0 (never drains in steady state).

typedef unsigned short u16;
typedef __attribute__((ext_vector_type(8))) short bf16x8;  // 8 bf16 = 4 VGPRs
typedef __attribute__((ext_vector_type(4))) float f32x4;

#define N_ROWS 32768
#define K_CENT 1000
#define KP     1024   // padded centroid count
#define DDIM   1024
#define NT     32     // K-tiles of BK=32

__device__ __forceinline__ u16 f2bf(float x) {
  unsigned u = __float_as_uint(x);
  u += 0x7fffu + ((u >> 16) & 1u);   // round-to-nearest-even
  return (u16)(u >> 16);
}

// async global->LDS, 16 B per lane. LDS dest is wave-uniform base; HW adds lane*16.
__device__ __forceinline__ void gload_lds16(const u16* g, u16* s) {
  __builtin_amdgcn_global_load_lds((__attribute__((address_space(1))) void*)g,
                                   (__attribute__((address_space(3))) void*)s,
                                   16, 0, 0);
}

// ---------------- prep kernels ----------------

__global__ __launch_bounds__(256) void prep_h(const float* __restrict__ h,
                                              u16* __restrict__ hb,
                                              float* __restrict__ hsq,
                                              float* __restrict__ rowsum) {
  const int row = blockIdx.x;
  const int t = threadIdx.x;
  const float4 v = reinterpret_cast<const float4*>(h + (size_t)row * DDIM)[t];
  ushort4 b;
  b.x = f2bf(v.x); b.y = f2bf(v.y); b.z = f2bf(v.z); b.w = f2bf(v.w);
  reinterpret_cast<ushort4*>(hb + (size_t)row * DDIM)[t] = b;
  float ss = v.x * v.x + v.y * v.y + v.z * v.z + v.w * v.w;
#pragma unroll
  for (int m = 1; m < 64; m <<= 1) ss += __shfl_xor(ss, m);
  __shared__ float sbuf[4];
  if ((t & 63) == 0) sbuf[t >> 6] = ss;
  __syncthreads();
  if (t == 0) {
    hsq[row] = sbuf[0] + sbuf[1] + sbuf[2] + sbuf[3];
    rowsum[row] = 0.0f;
  }
}

__global__ __launch_bounds__(256) void prep_c(const float* __restrict__ c,
                                              u16* __restrict__ cb,
                                              float* __restrict__ csq) {
  const int row = blockIdx.x;
  const int t = threadIdx.x;
  if (row < K_CENT) {
    const float4 v = reinterpret_cast<const float4*>(c + (size_t)row * DDIM)[t];
    ushort4 b;
    b.x = f2bf(v.x); b.y = f2bf(v.y); b.z = f2bf(v.z); b.w = f2bf(v.w);
    reinterpret_cast<ushort4*>(cb + (size_t)row * DDIM)[t] = b;
    float ss = v.x * v.x + v.y * v.y + v.z * v.z + v.w * v.w;
#pragma unroll
    for (int m = 1; m < 64; m <<= 1) ss += __shfl_xor(ss, m);
    __shared__ float sbuf[4];
    if ((t & 63) == 0) sbuf[t >> 6] = ss;
    __syncthreads();
    if (t == 0) csq[row] = sbuf[0] + sbuf[1] + sbuf[2] + sbuf[3];
  } else {
    ushort4 z; z.x = z.y = z.z = z.w = 0;
    reinterpret_cast<ushort4*>(cb + (size_t)row * DDIM)[t] = z;
    if (t == 0) csq[row] = 1e30f;  // pad rows: q ~ 1/(1+1e30) ~ 0
  }
}

// ---------------- main GEMM + q epilogue ----------------
// Tile 256 rows x 32 k = 1024 granules of 16 B per matrix per slot.
// Logical granule g = 4*row + j. Stored at p = g ^ ((g>>3)&7) (involution;
// 0 bank conflicts verified in R2/R3 profiles). global_load_lds writes
// linearly, so the per-lane GLOBAL source is pre-permuted by the same map.

__device__ __forceinline__ void stageA(const u16* __restrict__ gA, u16* sA,
                                       int tid, int t) {
#pragma unroll
  for (int i = 0; i < 2; ++i) {
    const int p = tid + i * 512;           // linear granule written
    const int g = p ^ ((p >> 3) & 7);      // logical granule fetched
    gload_lds16(gA + (size_t)(g >> 2) * DDIM + t * 32 + (g & 3) * 8,
                sA + (((tid & ~63) + i * 512) << 3));
  }
}
__device__ __forceinline__ void stageB(const u16* __restrict__ gB, u16* sB,
                                       int tid, int t) {
#pragma unroll
  for (int i = 0; i < 2; ++i) {
    const int p = tid + i * 512;
    const int g = p ^ ((p >> 3) & 7);
    gload_lds16(gB + (size_t)(g >> 2) * DDIM + t * 32 + (g & 3) * 8,
                sB + (((tid & ~63) + i * 512) << 3));
  }
}

__global__ __launch_bounds__(512, 2) void gemm_q(const u16* __restrict__ hb,
                                                 const u16* __restrict__ cb,
                                                 const float* __restrict__ hsq,
                                                 const float* __restrict__ csq,
                                                 float* __restrict__ out,
                                                 float* __restrict__ rowsum) {
  __shared__ u16 As[4][8192];  // 4 ring slots x (256x32) bf16 = 64 KB
  __shared__ u16 Bs[4][8192];  // 64 KB

  const int bid = blockIdx.x;
  // XCD swizzle: 512 blocks, 8 XCDs -> 64 consecutive per XCD.
  const int swz = ((bid & 7) << 6) | (bid >> 3);
  const int bcol = swz & 3;    // 4 col panels of 256 (KP=1024)
  const int brow = swz >> 2;   // 128 row panels of 256

  const int tid = threadIdx.x;
  const int w = tid >> 6;
  const int l = tid & 63;
  const int wm = w >> 2;       // 0..1 : 128-row half
  const int wn = w & 3;        // 0..3 : 64-col slice

  const u16* gA = hb + (size_t)brow * 256 * DDIM;
  const u16* gB = cb + (size_t)bcol * 256 * DDIM;

  // prologue: prefetch tiles 0..2 into slots 0..2 (12 loads/thread),
  // then drain tile 0 and barrier so ph1 reads of tile 0 are safe.
  stageA(gA, As[0], tid, 0); stageB(gB, Bs[0], tid, 0);
  stageA(gA, As[1], tid, 1); stageB(gB, Bs[1], tid, 1);
  stageA(gA, As[2], tid, 2); stageB(gB, Bs[2], tid, 2);

  // precomputed swizzled frag offsets (u16 elems, slot-relative)
  int aOff[8], bOff[4];
#pragma unroll
  for (int m = 0; m < 8; ++m) {
    const int row = wm * 128 + m * 16 + (l & 15);
    const int g = (row << 2) | (l >> 4);
    aOff[m] = (g ^ ((g >> 3) & 7)) << 3;
  }
#pragma unroll
  for (int n = 0; n < 4; ++n) {
    const int row = wn * 64 + n * 16 + (l & 15);
    const int g = (row << 2) | (l >> 4);
    bOff[n] = (g ^ ((g >> 3) & 7)) << 3;
  }

  f32x4 acc[8][4] = {};

  asm volatile("s_waitcnt vmcnt(8)" ::: "memory");
  __builtin_amdgcn_s_barrier();

  // ph1: {8 ds_read | stageA(T+3)} bar lgkm0 prio[16 MFMA m0-3] bar
  // ph2: {4 ds_read | stageB(T+3)} vmcnt(VM) bar lgkm0 prio[16 MFMA m4-7] bar
  // VM=8 steady (12 outstanding -> drain tile T+1's 4), tail 4,0,0.
#define KTILE(T, VMSTR)                                                        \
  {                                                                            \
    const int s_ = (T) & 3, ns_ = ((T) + 3) & 3;                               \
    const u16* SA_ = As[s_]; const u16* SB_ = Bs[s_];                          \
    bf16x8 aF[4], bF[4];                                                       \
    _Pragma("unroll") for (int n = 0; n < 4; ++n)                              \
        bF[n] = *(const bf16x8*)(SB_ + bOff[n]);                               \
    _Pragma("unroll") for (int m = 0; m < 4; ++m)                              \
        aF[m] = *(const bf16x8*)(SA_ + aOff[m]);                               \
    if ((T) + 3 < NT) stageA(gA, As[ns_], tid, (T) + 3);                       \
    __builtin_amdgcn_s_barrier();                                              \
    asm volatile("s_waitcnt lgkmcnt(0)" ::: "memory");                         \
    __builtin_amdgcn_s_setprio(1);                                             \
    _Pragma("unroll") for (int m = 0; m < 4; ++m)                              \
      _Pragma("unroll") for (int n = 0; n < 4; ++n)                            \
        acc[m][n] = __builtin_amdgcn_mfma_f32_16x16x32_bf16(aF[m], bF[n],      \
                                                            acc[m][n], 0, 0, 0); \
    __builtin_amdgcn_s_setprio(0);                                             \
    __builtin_amdgcn_s_barrier();                                              \
    _Pragma("unroll") for (int m = 0; m < 4; ++m)                              \
        aF[m] = *(const bf16x8*)(SA_ + aOff[m + 4]);                           \
    if ((T) + 3 < NT) stageB(gB, Bs[ns_], tid, (T) + 3);                       \
    asm volatile("s_waitcnt vmcnt(" VMSTR ")" ::: "memory");                   \
    __builtin_amdgcn_s_barrier();                                              \
    asm volatile("s_waitcnt lgkmcnt(0)" ::: "memory");                         \
    __builtin_amdgcn_s_setprio(1);                                             \
    _Pragma("unroll") for (int m = 0; m < 4; ++m)                              \
      _Pragma("unroll") for (int n = 0; n < 4; ++n)                            \
        acc[m + 4][n] = __builtin_amdgcn_mfma_f32_16x16x32_bf16(aF[m], bF[n],  \
                                                        acc[m + 4][n], 0, 0, 0); \
    __builtin_amdgcn_s_setprio(0);                                             \
    __builtin_amdgcn_s_barrier();                                              \
  }

  for (int t = 0; t < NT - 3; ++t) KTILE(t, "8")
  KTILE(NT - 3, "4")
  KTILE(NT - 2, "0")
  KTILE(NT - 1, "0")
#undef KTILE

  // Epilogue: C/D layout (16x16x32): col = l&15, row = (l>>4)*4 + reg
  const int gi0 = brow * 256 + wm * 128;
  const int gj0 = bcol * 256 + wn * 64;
  const int lr = (l >> 4) << 2;
  const int lc = l & 15;

#pragma unroll
  for (int m = 0; m < 8; ++m) {
    float hs[4];
#pragma unroll
    for (int r = 0; r < 4; ++r) hs[r] = hsq[gi0 + m * 16 + lr + r];
    float rs[4] = {0.f, 0.f, 0.f, 0.f};
#pragma unroll
    for (int n = 0; n < 4; ++n) {
      const int gj = gj0 + n * 16 + lc;
      const float cs = csq[gj];
#pragma unroll
      for (int r = 0; r < 4; ++r) {
        float d2 = hs[r] + cs - 2.0f * acc[m][n][r];
        d2 = fmaxf(d2, 0.0f);
        const float qv = 1.0f / (1.0f + d2);
        rs[r] += qv;
        if (gj < K_CENT)
          out[(size_t)(gi0 + m * 16 + lr + r) * K_CENT + gj] = qv;
      }
    }
#pragma unroll
    for (int r = 0; r < 4; ++r) {
      float v = rs[r];
      v += __shfl_xor(v, 1);
      v += __shfl_xor(v, 2);
      v += __shfl_xor(v, 4);
      v += __shfl_xor(v, 8);
      if (lc == 0) atomicAdd(&rowsum[gi0 + m * 16 + lr + r], v);
    }
  }
}

// ---------------- normalization ----------------

__global__ __launch_bounds__(256) void norm_k(float* __restrict__ out,
                                              const float* __restrict__ rowsum) {
  const int row = blockIdx.x;
  const int t = threadIdx.x;
  if (t < 250) {  // 1000 floats = 250 float4 per row
    const float inv = 1.0f / rowsum[row];
    float4* p = reinterpret_cast<float4*>(out) + (size_t)row * 250 + t;
    float4 v = *p;
    v.x *= inv; v.y *= inv; v.z *= inv; v.w *= inv;
    *p = v;
  }
}

// ---------------- launch ----------------

extern "C" void kernel_launch(void* const* d_in, const int* in_sizes, int n_in,
                              void* d_out, int out_size, void* d_ws, size_t ws_size,
                              hipStream_t stream) {
  const float* h   = (const float*)d_in[0];
  const float* cen = (const float*)d_in[1];
  float* out = (float*)d_out;
  char* ws = (char*)d_ws;

  u16*   cb     = (u16*)(ws);                           // 2 MB
  u16*   hb     = (u16*)(ws + 2097152);                 // 64 MB
  float* hsq    = (float*)(ws + 2097152 + 67108864);    // 128 KB
  float* csq    = (float*)(ws + 2097152 + 67108864 + 131072);   // 4 KB
  float* rowsum = (float*)(ws + 2097152 + 67108864 + 131072 + 4096); // 128 KB

  prep_c<<<KP, 256, 0, stream>>>(cen, cb, csq);
  prep_h<<<N_ROWS, 256, 0, stream>>>(h, hb, hsq, rowsum);
  gemm_q<<<(N_ROWS / 256) * (KP / 256), 512, 0, stream>>>(hb, cb, hsq, csq, out, rowsum);
  norm_k<<<N_ROWS, 256, 0, stream>>>(out, rowsum);
}

// Round 6
// 177.521 us; speedup vs baseline: 1.0388x; 1.0388x over previous
//
#include <hip/hip_runtime.h>

// DEC Student-t soft assignment, ALPHA=1 -> q_ij = 1/(1+d2_ij), row-normalized.
// d2 = ||h||^2 + ||c||^2 - 2 h.c ; cross term via bf16 MFMA, h_sq/c_sq exact fp32.
//
// R5 -> R6: register-level fragment double-buffering. R1/R3/R5 all serialized
// {LDS reads | MFMA} per tile (~1150 + ~1242 cyc) -> MfmaUtil pinned at 18.5%.
// Now each iter issues tile-T+1 frag ds_reads BEFORE tile-T MFMAs; the compiler
// inserts counted lgkm waits (no lgkmcnt(0)), so reads overlap MFMA. One raw
// s_barrier + counted vmcnt per tile for ring safety (reads prefetch dist 1,
// stages dist 3 => steady vmcnt(4), tail vmcnt(0)). sched_barrier(0) fences
// both sides of each barrier so nothing leaks across.

typedef unsigned short u16;
typedef __attribute__((ext_vector_type(8))) short bf16x8;  // 8 bf16 = 4 VGPRs
typedef __attribute__((ext_vector_type(4))) float f32x4;

#define N_ROWS 32768
#define K_CENT 1000
#define KP     1024   // padded centroid count
#define DDIM   1024
#define NT     32     // K-tiles of BK=32

__device__ __forceinline__ u16 f2bf(float x) {
  unsigned u = __float_as_uint(x);
  u += 0x7fffu + ((u >> 16) & 1u);   // round-to-nearest-even
  return (u16)(u >> 16);
}

// async global->LDS, 16 B per lane. LDS dest is wave-uniform base; HW adds lane*16.
__device__ __forceinline__ void gload_lds16(const u16* g, u16* s) {
  __builtin_amdgcn_global_load_lds((__attribute__((address_space(1))) void*)g,
                                   (__attribute__((address_space(3))) void*)s,
                                   16, 0, 0);
}

// ---------------- prep kernels ----------------

__global__ __launch_bounds__(256) void prep_h(const float* __restrict__ h,
                                              u16* __restrict__ hb,
                                              float* __restrict__ hsq,
                                              float* __restrict__ rowsum) {
  const int row = blockIdx.x;
  const int t = threadIdx.x;
  const float4 v = reinterpret_cast<const float4*>(h + (size_t)row * DDIM)[t];
  ushort4 b;
  b.x = f2bf(v.x); b.y = f2bf(v.y); b.z = f2bf(v.z); b.w = f2bf(v.w);
  reinterpret_cast<ushort4*>(hb + (size_t)row * DDIM)[t] = b;
  float ss = v.x * v.x + v.y * v.y + v.z * v.z + v.w * v.w;
#pragma unroll
  for (int m = 1; m < 64; m <<= 1) ss += __shfl_xor(ss, m);
  __shared__ float sbuf[4];
  if ((t & 63) == 0) sbuf[t >> 6] = ss;
  __syncthreads();
  if (t == 0) {
    hsq[row] = sbuf[0] + sbuf[1] + sbuf[2] + sbuf[3];
    rowsum[row] = 0.0f;
  }
}

__global__ __launch_bounds__(256) void prep_c(const float* __restrict__ c,
                                              u16* __restrict__ cb,
                                              float* __restrict__ csq) {
  const int row = blockIdx.x;
  const int t = threadIdx.x;
  if (row < K_CENT) {
    const float4 v = reinterpret_cast<const float4*>(c + (size_t)row * DDIM)[t];
    ushort4 b;
    b.x = f2bf(v.x); b.y = f2bf(v.y); b.z = f2bf(v.z); b.w = f2bf(v.w);
    reinterpret_cast<ushort4*>(cb + (size_t)row * DDIM)[t] = b;
    float ss = v.x * v.x + v.y * v.y + v.z * v.z + v.w * v.w;
#pragma unroll
    for (int m = 1; m < 64; m <<= 1) ss += __shfl_xor(ss, m);
    __shared__ float sbuf[4];
    if ((t & 63) == 0) sbuf[t >> 6] = ss;
    __syncthreads();
    if (t == 0) csq[row] = sbuf[0] + sbuf[1] + sbuf[2] + sbuf[3];
  } else {
    ushort4 z; z.x = z.y = z.z = z.w = 0;
    reinterpret_cast<ushort4*>(cb + (size_t)row * DDIM)[t] = z;
    if (t == 0) csq[row] = 1e30f;  // pad rows: q ~ 1/(1+1e30) ~ 0
  }
}

// ---------------- main GEMM + q epilogue ----------------
// Tile 256 rows x 32 k = 1024 granules of 16 B per matrix per slot.
// Logical granule g = 4*row + j. Stored at p = g ^ ((g>>3)&7) (involution;
// 0 bank conflicts verified in R2/R3/R5 profiles). global_load_lds writes
// linearly; the per-lane GLOBAL source is pre-permuted by the same map.

__device__ __forceinline__ void stageA(const u16* __restrict__ gA, u16* sA,
                                       int tid, int t) {
#pragma unroll
  for (int i = 0; i < 2; ++i) {
    const int p = tid + i * 512;           // linear granule written
    const int g = p ^ ((p >> 3) & 7);      // logical granule fetched
    gload_lds16(gA + (size_t)(g >> 2) * DDIM + t * 32 + (g & 3) * 8,
                sA + (((tid & ~63) + i * 512) << 3));
  }
}
__device__ __forceinline__ void stageB(const u16* __restrict__ gB, u16* sB,
                                       int tid, int t) {
#pragma unroll
  for (int i = 0; i < 2; ++i) {
    const int p = tid + i * 512;
    const int g = p ^ ((p >> 3) & 7);
    gload_lds16(gB + (size_t)(g >> 2) * DDIM + t * 32 + (g & 3) * 8,
                sB + (((tid & ~63) + i * 512) << 3));
  }
}

__global__ __launch_bounds__(512, 2) void gemm_q(const u16* __restrict__ hb,
                                                 const u16* __restrict__ cb,
                                                 const float* __restrict__ hsq,
                                                 const float* __restrict__ csq,
                                                 float* __restrict__ out,
                                                 float* __restrict__ rowsum) {
  __shared__ u16 As[4][8192];  // 4 ring slots x (256x32) bf16 = 64 KB
  __shared__ u16 Bs[4][8192];  // 64 KB

  const int bid = blockIdx.x;
  // XCD swizzle: 512 blocks, 8 XCDs -> 64 consecutive per XCD.
  const int swz = ((bid & 7) << 6) | (bid >> 3);
  const int bcol = swz & 3;    // 4 col panels of 256 (KP=1024)
  const int brow = swz >> 2;   // 128 row panels of 256

  const int tid = threadIdx.x;
  const int w = tid >> 6;
  const int l = tid & 63;
  const int wm = w >> 2;       // 0..1 : 128-row half
  const int wn = w & 3;        // 0..3 : 64-col slice

  const u16* gA = hb + (size_t)brow * 256 * DDIM;
  const u16* gB = cb + (size_t)bcol * 256 * DDIM;

  // prologue: prefetch tiles 0..2 into slots 0..2 (12 loads/thread)
  stageA(gA, As[0], tid, 0); stageB(gB, Bs[0], tid, 0);
  stageA(gA, As[1], tid, 1); stageB(gB, Bs[1], tid, 1);
  stageA(gA, As[2], tid, 2); stageB(gB, Bs[2], tid, 2);

  // precomputed swizzled frag offsets (u16 elems, slot-relative)
  int aOff[8], bOff[4];
#pragma unroll
  for (int m = 0; m < 8; ++m) {
    const int row = wm * 128 + m * 16 + (l & 15);
    const int g = (row << 2) | (l >> 4);
    aOff[m] = (g ^ ((g >> 3) & 7)) << 3;
  }
#pragma unroll
  for (int n = 0; n < 4; ++n) {
    const int row = wn * 64 + n * 16 + (l & 15);
    const int g = (row << 2) | (l >> 4);
    bOff[n] = (g ^ ((g >> 3) & 7)) << 3;
  }

  f32x4 acc[8][4] = {};

  // drain stages of tiles 0 AND 1 (iter 0 reads tile0 JIT + tile1 prefetch),
  // leave stage(2) in flight.
  asm volatile("s_waitcnt vmcnt(4)" ::: "memory");
  __builtin_amdgcn_s_barrier();
  __builtin_amdgcn_sched_barrier(0);

  bf16x8 fAa[4], fBa[4], fAb[4], fBb[4];
#pragma unroll
  for (int m = 0; m < 4; ++m) fAa[m] = *(const bf16x8*)(&As[0][0] + aOff[m]);
#pragma unroll
  for (int n = 0; n < 4; ++n) fBa[n] = *(const bf16x8*)(&Bs[0][0] + bOff[n]);

  // Per iter T: {JIT A4-7[T] | prefetch A0-3,B0-3[T+1] | stage(T+3)} then
  // 32 MFMA on regs (compiler inserts COUNTED lgkm waits), then
  // vmcnt(4) + s_barrier (drains stage(T+2); stage(T+3) stays in flight).
#define ITER(T, FAc, FBc, FAn, FBn, VMSTR, PREF, STAGE, SYNC)                  \
  {                                                                            \
    const int sc_ = (T) & 3, sn_ = ((T) + 1) & 3;                              \
    bf16x8 fA2[4];                                                             \
    _Pragma("unroll") for (int m = 0; m < 4; ++m)                              \
        fA2[m] = *(const bf16x8*)(&As[sc_][0] + aOff[m + 4]);                  \
    if (PREF) {                                                                \
      _Pragma("unroll") for (int m = 0; m < 4; ++m)                            \
          FAn[m] = *(const bf16x8*)(&As[sn_][0] + aOff[m]);                    \
      _Pragma("unroll") for (int n = 0; n < 4; ++n)                            \
          FBn[n] = *(const bf16x8*)(&Bs[sn_][0] + bOff[n]);                    \
    }                                                                          \
    if (STAGE) {                                                               \
      stageA(gA, As[((T) + 3) & 3], tid, (T) + 3);                             \
      stageB(gB, Bs[((T) + 3) & 3], tid, (T) + 3);                             \
    }                                                                          \
    __builtin_amdgcn_s_setprio(1);                                             \
    _Pragma("unroll") for (int m = 0; m < 4; ++m)                              \
      _Pragma("unroll") for (int n = 0; n < 4; ++n)                            \
        acc[m][n] = __builtin_amdgcn_mfma_f32_16x16x32_bf16(FAc[m], FBc[n],    \
                                                            acc[m][n], 0, 0, 0); \
    _Pragma("unroll") for (int m = 0; m < 4; ++m)                              \
      _Pragma("unroll") for (int n = 0; n < 4; ++n)                            \
        acc[m + 4][n] = __builtin_amdgcn_mfma_f32_16x16x32_bf16(fA2[m], FBc[n], \
                                                        acc[m + 4][n], 0, 0, 0); \
    __builtin_amdgcn_s_setprio(0);                                             \
    if (SYNC) {                                                                \
      __builtin_amdgcn_sched_barrier(0);                                       \
      asm volatile("s_waitcnt vmcnt(" VMSTR ")" ::: "memory");                 \
      __builtin_amdgcn_s_barrier();                                            \
      __builtin_amdgcn_sched_barrier(0);                                       \
    }                                                                          \
  }

#pragma unroll 1
  for (int t = 0; t < NT - 4; t += 2) {
    ITER(t,     fAa, fBa, fAb, fBb, "4", true, true, true)
    ITER(t + 1, fAb, fBb, fAa, fBa, "4", true, true, true)
  }
  ITER(NT - 4, fAa, fBa, fAb, fBb, "4", true, true,  true)   // T=28, stage(31)
  ITER(NT - 3, fAb, fBb, fAa, fBa, "0", true, false, true)   // T=29, drain all
  ITER(NT - 2, fAa, fBa, fAb, fBb, "0", true, false, false)  // T=30
  ITER(NT - 1, fAb, fBb, fAa, fBa, "0", false, false, false) // T=31
#undef ITER

  // Epilogue: C/D layout (16x16x32): col = l&15, row = (l>>4)*4 + reg
  const int gi0 = brow * 256 + wm * 128;
  const int gj0 = bcol * 256 + wn * 64;
  const int lr = (l >> 4) << 2;
  const int lc = l & 15;

#pragma unroll
  for (int m = 0; m < 8; ++m) {
    float hs[4];
#pragma unroll
    for (int r = 0; r < 4; ++r) hs[r] = hsq[gi0 + m * 16 + lr + r];
    float rs[4] = {0.f, 0.f, 0.f, 0.f};
#pragma unroll
    for (int n = 0; n < 4; ++n) {
      const int gj = gj0 + n * 16 + lc;
      const float cs = csq[gj];
#pragma unroll
      for (int r = 0; r < 4; ++r) {
        float d2 = hs[r] + cs - 2.0f * acc[m][n][r];
        d2 = fmaxf(d2, 0.0f);
        const float qv = 1.0f / (1.0f + d2);
        rs[r] += qv;
        if (gj < K_CENT)
          out[(size_t)(gi0 + m * 16 + lr + r) * K_CENT + gj] = qv;
      }
    }
#pragma unroll
    for (int r = 0; r < 4; ++r) {
      float v = rs[r];
      v += __shfl_xor(v, 1);
      v += __shfl_xor(v, 2);
      v += __shfl_xor(v, 4);
      v += __shfl_xor(v, 8);
      if (lc == 0) atomicAdd(&rowsum[gi0 + m * 16 + lr + r], v);
    }
  }
}

// ---------------- normalization ----------------

__global__ __launch_bounds__(256) void norm_k(float* __restrict__ out,
                                              const float* __restrict__ rowsum) {
  const int row = blockIdx.x;
  const int t = threadIdx.x;
  if (t < 250) {  // 1000 floats = 250 float4 per row
    const float inv = 1.0f / rowsum[row];
    float4* p = reinterpret_cast<float4*>(out) + (size_t)row * 250 + t;
    float4 v = *p;
    v.x *= inv; v.y *= inv; v.z *= inv; v.w *= inv;
    *p = v;
  }
}

// ---------------- launch ----------------

extern "C" void kernel_launch(void* const* d_in, const int* in_sizes, int n_in,
                              void* d_out, int out_size, void* d_ws, size_t ws_size,
                              hipStream_t stream) {
  const float* h   = (const float*)d_in[0];
  const float* cen = (const float*)d_in[1];
  float* out = (float*)d_out;
  char* ws = (char*)d_ws;

  u16*   cb     = (u16*)(ws);                           // 2 MB
  u16*   hb     = (u16*)(ws + 2097152);                 // 64 MB
  float* hsq    = (float*)(ws + 2097152 + 67108864);    // 128 KB
  float* csq    = (float*)(ws + 2097152 + 67108864 + 131072);   // 4 KB
  float* rowsum = (float*)(ws + 2097152 + 67108864 + 131072 + 4096); // 128 KB

  prep_c<<<KP, 256, 0, stream>>>(cen, cb, csq);
  prep_h<<<N_ROWS, 256, 0, stream>>>(h, hb, hsq, rowsum);
  gemm_q<<<(N_ROWS / 256) * (KP / 256), 512, 0, stream>>>(hb, cb, hsq, csq, out, rowsum);
  norm_k<<<N_ROWS, 256, 0, stream>>>(out, rowsum);
}